// Round 3
// baseline (63.772 us; speedup 1.0000x reference)
//
#include <hip/hip_runtime.h>
#include <stdint.h>

// Tropical (max-plus) matmul: Y[b][j] = max_k X[b][k] + W[j][k]
// M=512, N=1024, K=1024, fp32 in/out.
//
// Exact candidate pruning: with any D >= max_j (max_k W[j,k] - min_k W[j,k]),
// k with X[b,k] <= Xmax_b - D loses to k* = argmax X[b,:] for every j.
// Global spread D'' = max(W) - min(W) >= that bound (still exact; ~1.4
// candidates/row at W = randn*0.02). CAP overflow -> coalesced full-scan
// fallback keeps the kernel exact for ANY input.
//
// R19 (vs R18 @63.36us): K2 latency-chain cuts. Model: total = 41us harness
// ws-poison (256MiB @82% HBM peak, fixed) + ~17us dispatch overhead (fixed)
// + ~4us kernels. Only lever: K2's serial chain. Changes:
//   - argmax column k* is ALWAYS a candidate (Xmax > Xmax-D); carry the index
//     through the max butterfly and issue the Wt[k*] row load BEFORE thr/D
//     resolve -> the dominant L3 gather latency overlaps candidate selection.
//   - drop the 4KB sX LDS staging (fallback re-reads X from global; prob~0).
// If this probe lands within noise, the overhead-floor model is confirmed.

#define M_DIM 512
#define N_DIM 1024
#define K_DIM 1024
#define CAP 128

// ws layout: Wt 4MB | tmax 1KB | tmin 1KB
#define OFF_WT    0
#define OFF_TMAX  (4u * 1024u * 1024u)
#define OFF_TMIN  (OFF_TMAX + 1024u)

// ---- K1: transpose 64x64 W-tile + tile min/max (256 blocks) ----
__global__ __launch_bounds__(256)
void prep(const float* __restrict__ W, float* __restrict__ Wt,
          float* __restrict__ tmax, float* __restrict__ tmin) {
    __shared__ float L[64][65];     // +1 pad
    __shared__ float smx[4][64];
    __shared__ float smn[4][64];

    const int tid = threadIdx.x;
    const int bx = blockIdx.x;
    const int kt = bx & 15;
    const int jt = bx >> 4;
    const int k0 = kt * 64, j0 = jt * 64;

    {   // load: j-row r, 16 k's per thread
        const int r = tid >> 2, q = tid & 3;
        const float* g = &W[(size_t)(j0 + r) * K_DIM + k0 + q * 16];
#pragma unroll
        for (int t = 0; t < 4; t++) {
            float4 f = *(const float4*)(g + 4 * t);
            L[r][q * 16 + 4 * t + 0] = f.x;
            L[r][q * 16 + 4 * t + 1] = f.y;
            L[r][q * 16 + 4 * t + 2] = f.z;
            L[r][q * 16 + 4 * t + 3] = f.w;
        }
    }
    __syncthreads();
    {   // write Wt tile: k-row kk, 16 j's per thread
        const int kk = tid >> 2, q = tid & 3;
        float* o = &Wt[(size_t)(k0 + kk) * N_DIM + j0 + q * 16];
#pragma unroll
        for (int t = 0; t < 4; t++) {
            float4 f = {L[q * 16 + 4 * t + 0][kk], L[q * 16 + 4 * t + 1][kk],
                        L[q * 16 + 4 * t + 2][kk], L[q * 16 + 4 * t + 3][kk]};
            *(float4*)(o + 4 * t) = f;
        }
    }
    {   // per-j partial min/max (4 threads/j), then tile-global reduce
        const int jl = tid & 63, seg = tid >> 6;
        float mx = -3.0e38f, mn = 3.0e38f;
#pragma unroll
        for (int i = 0; i < 16; i++) {
            float v = L[jl][seg * 16 + i];
            mx = fmaxf(mx, v);
            mn = fminf(mn, v);
        }
        smx[seg][jl] = mx;
        smn[seg][jl] = mn;
    }
    __syncthreads();
    if (tid < 64) {
        float mx = fmaxf(fmaxf(smx[0][tid], smx[1][tid]), fmaxf(smx[2][tid], smx[3][tid]));
        float mn = fminf(fminf(smn[0][tid], smn[1][tid]), fminf(smn[2][tid], smn[3][tid]));
#pragma unroll
        for (int off = 32; off > 0; off >>= 1) {
            mx = fmaxf(mx, __shfl_down(mx, off, 64));
            mn = fminf(mn, __shfl_down(mn, off, 64));
        }
        if (tid == 0) {
            const int id = jt * 16 + kt;
            tmax[id] = mx;
            tmin[id] = mn;
        }
    }
}

// ---- K2: D (wave-0), Xmax+argmax (in-block), speculative k* gather, emit ----
__global__ __launch_bounds__(256)
void emit_pruned(const float* __restrict__ X, const float* __restrict__ Wt,
                 const float* __restrict__ tmax, const float* __restrict__ tmin,
                 float* __restrict__ out) {
    __shared__ float sD;
    __shared__ float sXm[4];
    __shared__ int   sXi[4];
    __shared__ float sval[CAP];
    __shared__ int   sidx[CAP];
    __shared__ int   scnt;

    const int tid = threadIdx.x;
    const int b = blockIdx.x;

    // issue the X row load first (root of the critical chain)
    const float4 xv = ((const float4*)X)[b * (K_DIM / 4) + tid];

    // --- wave 0: D'' = max(W) - min(W) from 256 tile pairs, butterfly ---
    if (tid < 64) {
        float4 a = ((const float4*)tmax)[tid];
        float4 i = ((const float4*)tmin)[tid];
        float mx = fmaxf(fmaxf(a.x, a.y), fmaxf(a.z, a.w));
        float mn = fminf(fminf(i.x, i.y), fminf(i.z, i.w));
#pragma unroll
        for (int off = 32; off > 0; off >>= 1) {
            mx = fmaxf(mx, __shfl_down(mx, off, 64));
            mn = fminf(mn, __shfl_down(mn, off, 64));
        }
        if (tid == 0) sD = (mx - mn) * 1.0001f + 1e-6f;  // pad vs fp rounding
    }
    if (tid == 0) scnt = 0;

    // --- Xmax_b + argmax via (value,index) butterfly ---
    const float xa[4] = {xv.x, xv.y, xv.z, xv.w};
    float m = xa[0];
    int mi = tid * 4;
#pragma unroll
    for (int c = 1; c < 4; c++)
        if (xa[c] > m) { m = xa[c]; mi = tid * 4 + c; }
#pragma unroll
    for (int off = 32; off > 0; off >>= 1) {
        float om = __shfl_xor(m, off, 64);
        int oi = __shfl_xor(mi, off, 64);
        if (om > m) { m = om; mi = oi; }
    }
    if ((tid & 63) == 0) { sXm[tid >> 6] = m; sXi[tid >> 6] = mi; }
    __syncthreads();

    float xm = sXm[0];
    int ks = sXi[0];
#pragma unroll
    for (int w = 1; w < 4; w++)
        if (sXm[w] > xm) { xm = sXm[w]; ks = sXi[w]; }

    // speculative gather: k* is always a candidate -> issue its row NOW,
    // before thr / the candidate list resolve.
    const float4 w0 = ((const float4*)Wt)[ks * (N_DIM / 4) + tid];

    const float thr = xm - sD;

    // --- candidate list (excluding k*, already in flight) ---
#pragma unroll
    for (int c = 0; c < 4; c++) {
        const int k = tid * 4 + c;
        if (xa[c] > thr && k != ks) {
            int p = atomicAdd(&scnt, 1);
            if (p < CAP) { sidx[p] = k; sval[p] = xa[c]; }
        }
    }
    __syncthreads();
    const int n = scnt;

    // --- emit ---
    float4 acc;
    acc.x = xm + w0.x;
    acc.y = xm + w0.y;
    acc.z = xm + w0.z;
    acc.w = xm + w0.w;
    if (n <= CAP) {
        for (int c = 0; c < n; c++) {
            const int k = sidx[c];
            const float xk = sval[c];
            const float4 w = ((const float4*)Wt)[k * (N_DIM / 4) + tid];
            acc.x = fmaxf(acc.x, xk + w.x);
            acc.y = fmaxf(acc.y, xk + w.y);
            acc.z = fmaxf(acc.z, xk + w.z);
            acc.w = fmaxf(acc.w, xk + w.w);
        }
    } else {
        // overflow fallback (prob ~0): exact full scan, still coalesced on Wt;
        // X re-read from global (scalar broadcast loads, L2-resident).
        for (int k = 0; k < K_DIM; k++) {
            const float xk = X[(size_t)b * K_DIM + k];
            const float4 w = ((const float4*)Wt)[k * (N_DIM / 4) + tid];
            acc.x = fmaxf(acc.x, xk + w.x);
            acc.y = fmaxf(acc.y, xk + w.y);
            acc.z = fmaxf(acc.z, xk + w.z);
            acc.w = fmaxf(acc.w, xk + w.w);
        }
    }
    ((float4*)out)[b * (N_DIM / 4) + tid] = acc;
}

extern "C" void kernel_launch(void* const* d_in, const int* in_sizes, int n_in,
                              void* d_out, int out_size, void* d_ws, size_t ws_size,
                              hipStream_t stream) {
    const float* X = (const float*)d_in[0];   // [512][1024]
    const float* W = (const float*)d_in[1];   // [1024][1024]
    float* out = (float*)d_out;               // [512][1024]

    char* ws = (char*)d_ws;
    float* Wt   = (float*)(ws + OFF_WT);
    float* tmax = (float*)(ws + OFF_TMAX);
    float* tmin = (float*)(ws + OFF_TMIN);

    prep<<<256, 256, 0, stream>>>(W, Wt, tmax, tmin);
    emit_pruned<<<M_DIM, 256, 0, stream>>>(X, Wt, tmax, tmin, out);
}